// Round 6
// baseline (6048.738 us; speedup 1.0000x reference)
//
#include <hip/hip_runtime.h>
#include <cmath>

#define B_   128
#define T_   100
#define IN_  512
#define H_   1024
#define E_   8
#define HH_  512
#define GIN_ 5
#define GH_  8

typedef unsigned long long u64t;

__device__ __forceinline__ float sigf(float x) { return 1.0f / (1.0f + expf(-x)); }

#define DOT4(a, xv, wv)                                              \
  a = fmaf((xv).x, (wv).x, a); a = fmaf((xv).y, (wv).y, a);          \
  a = fmaf((xv).z, (wv).z, a); a = fmaf((xv).w, (wv).w, a);

// Agent-scope (sc1) 16B load: bypasses stale per-XCD L2 (fallback tier only).
__device__ __forceinline__ float4 ld_h4_sc1(const float4* p) {
  const u64t* q = (const u64t*)p;
  u64t a = __hip_atomic_load(q,     __ATOMIC_RELAXED, __HIP_MEMORY_SCOPE_AGENT);
  u64t b = __hip_atomic_load(q + 1, __ATOMIC_RELAXED, __HIP_MEMORY_SCOPE_AGENT);
  union { u64t u; float2 f; } ca, cb;
  ca.u = a; cb.u = b;
  return make_float4(ca.f.x, ca.f.y, cb.f.x, cb.f.y);
}

// Grid barrier without cache invalidation (h visibility handled by sc1 stores
// + first-touch plain loads of per-step ring buffers).
__device__ __forceinline__ void gridbar(unsigned* c) {
  __syncthreads();   // drains vmcnt: all sc1 h-stores have reached the LLC
  if (threadIdx.x == 0) {
    __hip_atomic_fetch_add(c, 1u, __ATOMIC_RELEASE, __HIP_MEMORY_SCOPE_AGENT);
    while (__hip_atomic_load(c, __ATOMIC_RELAXED, __HIP_MEMORY_SCOPE_AGENT) < gridDim.x) {
      __builtin_amdgcn_s_sleep(1);
    }
  }
  __syncthreads();
}

// Transpose X[b][t][0:512] -> XT4[t][kq][b].
__global__ __launch_bounds__(256) void xt_kernel(
    const float* __restrict__ X, float4* __restrict__ XT4)
{
  int idx = blockIdx.x * 256 + threadIdx.x;     // over 100*128*128
  int b  = idx & 127;
  int kq = (idx >> 7) & 127;
  int t  = idx >> 14;
  XT4[idx] = *(const float4*)(X + ((size_t)b * T_ + t) * IN_ + kq * 4);
}

// wave-uniform weight rows (scalarized to s_load: per-gate base + imm offsets)
#define ROWX(g, jj) ((const float4*)(wih) + (((size_t)((g) * H_ + j0 + (jj))) << 7))
#define ROWH(g, jj) ((const float4*)(whh) + (((size_t)((g) * H_ + j0 + (jj))) << 8))

// Persistent main GRU: 256 blocks x 1024 threads (16 waves, 4/SIMD), 1 block/CU.
// Block: 8 j-cols x 64 batches, waves split K 16 ways (no duplicate x/h reads).
// XCD-swizzled j-tiles: per-XCD weight footprint 2.36 MB (L2-resident, never
// invalidated). RING=true: per-step h buffers, plain L2-cached h loads.
// RING=false: 2-buffer ping-pong with sc1 h loads.
template<bool RING>
__global__ __launch_bounds__(1024, 4) void gru_persist2(
    const float* __restrict__ X, const float4* __restrict__ XT4, int use_xt,
    const float* __restrict__ wih, const float* __restrict__ whh,
    const float* __restrict__ bih, const float* __restrict__ bhh,
    float* __restrict__ ring,                     // [R][H/4][128] float4
    unsigned* __restrict__ barr)
{
  extern __shared__ float4 red4[];                // [16][8][64] = 128 KB

  const int tid  = threadIdx.x;
  const int lane = tid & 63;
  const int ks   = __builtin_amdgcn_readfirstlane(tid >> 6);   // 0..15
  const int bid  = blockIdx.x;
  // XCD-aware: xcd = bid&7 owns j-cols [xcd*128, (xcd+1)*128)
  const int xcd  = bid & 7;
  const int s    = bid >> 3;                      // 0..31
  const int j0   = (xcd * 16 + (s >> 1)) * 8;
  const int b0   = (s & 1) * 64;

  // epilogue mapping + biases (threads 0..511: jl 0..7 x b 0..63)
  const int ejl = tid >> 6;                       // valid when tid<512
  const int eb  = tid & 63;
  float bir = 0.f, biz = 0.f, bin = 0.f, bhr = 0.f, bhz = 0.f, bhn = 0.f;
  if (tid < 512) {
    const int j = j0 + ejl;
    bir = bih[j]; biz = bih[H_ + j]; bin = bih[2 * H_ + j];
    bhr = bhh[j]; bhz = bhh[H_ + j]; bhn = bhh[2 * H_ + j];
  }

  for (int t = 0; t < T_; ++t) {
    const float4* __restrict__ hp4 =
        (const float4*)ring + (size_t)(RING ? t : (t & 1)) * 32768;
    float* __restrict__ hnf =
        ring + (size_t)(RING ? (t + 1) : ((t + 1) & 1)) * 131072;

    float aR[8] = {}, aZ[8] = {}, aNX[8] = {}, aNH[8] = {};

    // ---- X phase: 8 x-quads per wave (128 over 16 waves)
    if (use_xt) {
      const float4* __restrict__ xt = XT4 + (size_t)t * 16384 + b0 + lane;
      #pragma unroll 4
      for (int i = 0; i < 8; ++i) {
        const int q = ks * 8 + i;
        const float4 xv = xt[q * 128];
        #pragma unroll
        for (int g = 0; g < 3; ++g) {
          #pragma unroll
          for (int jj = 0; jj < 8; ++jj) {
            const float4 w = ROWX(g, jj)[q];
            float& A = (g == 0) ? aR[jj] : (g == 1) ? aZ[jj] : aNX[jj];
            DOT4(A, xv, w);
          }
        }
      }
    } else {
      const float* xr = X + ((size_t)(b0 + lane) * T_ + t) * IN_;
      #pragma unroll 4
      for (int i = 0; i < 8; ++i) {
        const int q = ks * 8 + i;
        const float4 xv = *(const float4*)(xr + q * 4);
        #pragma unroll
        for (int g = 0; g < 3; ++g) {
          #pragma unroll
          for (int jj = 0; jj < 8; ++jj) {
            const float4 w = ROWX(g, jj)[q];
            float& A = (g == 0) ? aR[jj] : (g == 1) ? aZ[jj] : aNX[jj];
            DOT4(A, xv, w);
          }
        }
      }
    }

    // ---- H phase: 16 h-quads per wave (256 over 16 waves)
    {
      const float4* __restrict__ hb = hp4 + b0 + lane;
      #pragma unroll 4
      for (int i = 0; i < 16; ++i) {
        const int q = ks * 16 + i;
        const float4 xv = RING ? hb[q * 128] : ld_h4_sc1(hb + q * 128);
        #pragma unroll
        for (int g = 0; g < 3; ++g) {
          #pragma unroll
          for (int jj = 0; jj < 8; ++jj) {
            const float4 w = ROWH(g, jj)[q];
            float& A = (g == 0) ? aR[jj] : (g == 1) ? aZ[jj] : aNH[jj];
            DOT4(A, xv, w);
          }
        }
      }
    }

    // ---- 16-way cross-wave K reduction via LDS
    #pragma unroll
    for (int jj = 0; jj < 8; ++jj)
      red4[(ks * 8 + jj) * 64 + lane] = make_float4(aR[jj], aZ[jj], aNX[jj], aNH[jj]);
    __syncthreads();

    if (tid < 512) {
      float sr = 0.f, sz = 0.f, sx = 0.f, sh = 0.f;
      #pragma unroll
      for (int k2 = 0; k2 < 16; ++k2) {
        float4 v = red4[(k2 * 8 + ejl) * 64 + eb];
        sr += v.x; sz += v.y; sx += v.z; sh += v.w;
      }
      float r = sigf(sr + bir + bhr);
      float z = sigf(sz + biz + bhz);
      float n = tanhf(sx + bin + r * (sh + bhn));
      const int j = j0 + ejl;
      const int hidx = (((j >> 2) * 128 + b0 + eb) << 2) + (j & 3);
      float hpv;
      if (RING) hpv = ((const float*)hp4)[hidx];
      else      hpv = __hip_atomic_load(&((const float*)hp4)[hidx],
                                        __ATOMIC_RELAXED, __HIP_MEMORY_SCOPE_AGENT);
      float hv = (1.f - z) * n + z * hpv;
      // sc1 store: write-through so the LLC (coherence point) has it
      __hip_atomic_store(&hnf[hidx], hv, __ATOMIC_RELAXED, __HIP_MEMORY_SCOPE_AGENT);
    }

    gridbar(barr + t);
  }
}

// Final h4T -> hfin[b][k]
__global__ __launch_bounds__(256) void hfin_kernel(
    const float* __restrict__ h4, float* __restrict__ out)
{
  int idx = blockIdx.x * 256 + threadIdx.x;   // over 128*1024
  int b = idx >> 10, k = idx & 1023;
  out[idx] = h4[(((k >> 2) * 128 + b) << 2) + (k & 3)];
}

// Gating GRUs: one wave per batch, gate-per-lane, all state in regs.
__global__ __launch_bounds__(64, 1) void gating_kernel(
    const float* __restrict__ X,
    const float* __restrict__ gwih0, const float* __restrict__ gwhh0,
    const float* __restrict__ gbih0, const float* __restrict__ gbhh0,
    const float* __restrict__ gwih1, const float* __restrict__ gwhh1,
    const float* __restrict__ gbih1, const float* __restrict__ gbhh1,
    float* __restrict__ omega)
{
  const int b = blockIdx.x;
  const int g = threadIdx.x;
  const int u = g & 7;
  float wi0[GIN_] = {}, wh0[GH_] = {}, wi1[GH_] = {}, wh1[GH_] = {};
  float bi0 = 0.f, bh0 = 0.f, bi1 = 0.f, bh1 = 0.f;
  if (g < 3 * GH_) {
    #pragma unroll
    for (int i = 0; i < GIN_; ++i) wi0[i] = gwih0[g * GIN_ + i];
    #pragma unroll
    for (int k = 0; k < GH_; ++k) { wh0[k] = gwhh0[g * GH_ + k]; wi1[k] = gwih1[g * GH_ + k]; wh1[k] = gwhh1[g * GH_ + k]; }
    bi0 = gbih0[g]; bh0 = gbhh0[g]; bi1 = gbih1[g]; bh1 = gbhh1[g];
  }
  float h0[GH_] = {}, h1[GH_] = {};
  for (int t = 0; t < T_; ++t) {
    float xt[GIN_];
    #pragma unroll
    for (int i = 0; i < GIN_; ++i) xt[i] = X[((size_t)b * T_ + t) * IN_ + (IN_ - GIN_) + i];
    float px = bi0, ph = bh0;
    #pragma unroll
    for (int i = 0; i < GIN_; ++i) px = fmaf(xt[i], wi0[i], px);
    #pragma unroll
    for (int k = 0; k < GH_; ++k) ph = fmaf(h0[k], wh0[k], ph);
    float s = px + ph;
    float s_r = __shfl(s, u);
    float s_z = __shfl(s, 8 + u);
    float nval = tanhf(px + sigf(s_r) * ph);
    float zval = sigf(s_z);
    float hnew = (1.f - zval) * nval + zval * h0[u];
    #pragma unroll
    for (int k = 0; k < GH_; ++k) h0[k] = __shfl(hnew, 16 + k);
    float px1 = bi1, ph1 = bh1;
    #pragma unroll
    for (int k = 0; k < GH_; ++k) px1 = fmaf(h0[k], wi1[k], px1);
    #pragma unroll
    for (int k = 0; k < GH_; ++k) ph1 = fmaf(h1[k], wh1[k], ph1);
    float s1 = px1 + ph1;
    float s1r = __shfl(s1, u);
    float s1z = __shfl(s1, 8 + u);
    float n1 = tanhf(px1 + sigf(s1r) * ph1);
    float z1 = sigf(s1z);
    float h1new = (1.f - z1) * n1 + z1 * h1[u];
    #pragma unroll
    for (int k = 0; k < GH_; ++k) h1[k] = __shfl(h1new, 16 + k);
  }
  if (g < GH_) {
    float m = h1[0];
    #pragma unroll
    for (int k = 1; k < GH_; ++k) m = fmaxf(m, h1[k]);
    float sum = 0.f;
    #pragma unroll
    for (int k = 0; k < GH_; ++k) sum += expf(h1[k] - m);
    omega[b * GH_ + g] = expf(h1[g] - m) / sum;
  }
}

// MoE layer: out[b,j] = act( sum_e omega[b,e] * (dot(in[b,:],w[e,:,j]) + bias[e,j]) )
__global__ __launch_bounds__(256, 2) void moe_kernel(
    const float* __restrict__ in, const float* __restrict__ w,
    const float* __restrict__ bias, const float* __restrict__ omega,
    float* __restrict__ out, int K, int act)
{
  __shared__ float4 lin4[64 * 32];
  __shared__ float  ldsw[E_ * 4 * 128];
  const int tid  = threadIdx.x;
  const int bh   = blockIdx.x & 1;
  const int jt   = blockIdx.x >> 1;
  const int wv   = tid >> 6;
  const int lane = tid & 63;
  const int j0   = jt * 4;
  const int j    = __builtin_amdgcn_readfirstlane(j0 + wv);
  const int b    = bh * 64 + lane;

  float acc[E_] = {0.f,0.f,0.f,0.f,0.f,0.f,0.f,0.f};
  const float4* row4 = &lin4[lane * 32];
  const int nch = K / 128;

  for (int c = 0; c < nch; ++c) {
    __syncthreads();
    const int k0 = c * 128;
    #pragma unroll
    for (int it = 0; it < 8; ++it) {
      int f = it * 256 + tid;
      int bb = f >> 5, q = f & 31;
      float4 v = *(const float4*)(in + (size_t)(bh * 64 + bb) * K + k0 + q * 4);
      lin4[bb * 32 + ((q & 24) | ((q ^ bb) & 7))] = v;
    }
    #pragma unroll
    for (int it = 0; it < 4; ++it) {
      int f = it * 256 + tid;
      int e = f >> 7, k = f & 127;
      float4 v = *(const float4*)(w + ((size_t)e * K + k0 + k) * HH_ + j0);
      ldsw[(e * 4 + 0) * 128 + k] = v.x;
      ldsw[(e * 4 + 1) * 128 + k] = v.y;
      ldsw[(e * 4 + 2) * 128 + k] = v.z;
      ldsw[(e * 4 + 3) * 128 + k] = v.w;
    }
    __syncthreads();
    #pragma unroll 2
    for (int q = 0; q < 32; ++q) {
      float4 xv = row4[(q & 24) | ((q ^ lane) & 7)];
      #pragma unroll
      for (int e = 0; e < E_; ++e) {
        const float4 wq = *(const float4*)&ldsw[(e * 4 + wv) * 128 + 4 * q];
        acc[e] = fmaf(xv.x, wq.x, acc[e]);
        acc[e] = fmaf(xv.y, wq.y, acc[e]);
        acc[e] = fmaf(xv.z, wq.z, acc[e]);
        acc[e] = fmaf(xv.w, wq.w, acc[e]);
      }
    }
  }

  float om[E_];
  #pragma unroll
  for (int e = 0; e < E_; ++e) om[e] = omega[b * E_ + e];
  float v = 0.f;
  #pragma unroll
  for (int e = 0; e < E_; ++e) v = fmaf(om[e], acc[e] + bias[e * HH_ + j], v);
  if (act == 0) v = (v > 0.f) ? v : expm1f(v);
  else          v = fminf(fmaxf(v, 0.f), 1.f);
  out[(size_t)b * HH_ + j] = v;
}

extern "C" void kernel_launch(void* const* d_in, const int* in_sizes, int n_in,
                              void* d_out, int out_size, void* d_ws, size_t ws_size,
                              hipStream_t stream) {
  (void)in_sizes; (void)n_in; (void)out_size;
  const float* X     = (const float*)d_in[0];
  const float* gwih0 = (const float*)d_in[1];
  const float* gwhh0 = (const float*)d_in[2];
  const float* gbih0 = (const float*)d_in[3];
  const float* gbhh0 = (const float*)d_in[4];
  const float* gwih1 = (const float*)d_in[5];
  const float* gwhh1 = (const float*)d_in[6];
  const float* gbih1 = (const float*)d_in[7];
  const float* gbhh1 = (const float*)d_in[8];
  const float* mwih  = (const float*)d_in[9];
  const float* mwhh  = (const float*)d_in[10];
  const float* mbih  = (const float*)d_in[11];
  const float* mbhh  = (const float*)d_in[12];
  const float* w1    = (const float*)d_in[13];
  const float* b1    = (const float*)d_in[14];
  const float* w2    = (const float*)d_in[15];
  const float* b2    = (const float*)d_in[16];
  const float* w3    = (const float*)d_in[17];
  const float* b3    = (const float*)d_in[18];

  const size_t HBUF = (size_t)B_ * H_;                  // 131072 floats
  const size_t XTF  = (size_t)T_ * IN_ * B_;            // 6.55M floats
  // tier A (ring): barr + 101 h-bufs + hfin + om + a1 + a2 + XT
  size_t ringA = 256 + (size_t)(T_ + 1) * HBUF + HBUF + 1024 + 2 * (size_t)B_ * HH_ + XTF;
  // tier B (pingpong): 2 h-bufs instead of 101
  size_t ringB = 256 + 2 * HBUF + HBUF + 1024 + 2 * (size_t)B_ * HH_ + XTF;
  int tierA   = ws_size >= ringA * sizeof(float);
  int use_xt  = tierA || (ws_size >= ringB * sizeof(float));
  int R       = tierA ? (T_ + 1) : 2;

  float* ws = (float*)d_ws;
  unsigned* barr = (unsigned*)ws;
  float* ring = ws + 256;
  float* hfin = ring + (size_t)R * HBUF;
  float* om   = hfin + HBUF;
  float* a1   = om + 1024;
  float* a2   = a1 + (size_t)B_ * HH_;
  float* XT   = a2 + (size_t)B_ * HH_;

  // zero: barrier slots + ring[0] (initial hidden state)
  hipMemsetAsync(d_ws, 0, (256 + HBUF) * sizeof(float), stream);
  hipFuncSetAttribute((const void*)gru_persist2<true>,
                      hipFuncAttributeMaxDynamicSharedMemorySize, 131072);
  hipFuncSetAttribute((const void*)gru_persist2<false>,
                      hipFuncAttributeMaxDynamicSharedMemorySize, 131072);

  gating_kernel<<<128, 64, 0, stream>>>(X, gwih0, gwhh0, gbih0, gbhh0,
                                        gwih1, gwhh1, gbih1, gbhh1, om);
  if (use_xt)
    xt_kernel<<<(T_ * 128 * 128) / 256, 256, 0, stream>>>(X, (float4*)XT);

  if (tierA)
    gru_persist2<true><<<256, 1024, 131072, stream>>>(X, (const float4*)XT, use_xt,
        mwih, mwhh, mbih, mbhh, ring, barr);
  else
    gru_persist2<false><<<256, 1024, 131072, stream>>>(X, (const float4*)XT, use_xt,
        mwih, mwhh, mbih, mbhh, ring, barr);

  const float* hlast = ring + (size_t)(tierA ? T_ : (T_ & 1)) * HBUF;
  hfin_kernel<<<512, 256, 0, stream>>>(hlast, hfin);
  moe_kernel<<<256, 256, 0, stream>>>(hfin, w1, b1, om, a1, H_, 0);
  moe_kernel<<<256, 256, 0, stream>>>(a1, w2, b2, om, a2, HH_, 0);
  moe_kernel<<<256, 256, 0, stream>>>(a2, w3, b3, om, (float*)d_out, HH_, 1);
}

// Round 7
// 3437.402 us; speedup vs baseline: 1.7597x; 1.7597x over previous
//
#include <hip/hip_runtime.h>
#include <cmath>

#define B_   128
#define T_   100
#define IN_  512
#define H_   1024
#define E_   8
#define HH_  512
#define GIN_ 5
#define GH_  8
#define WQ_  4608          // weight float4s per block (4 j x 3 g x 384 q)

typedef unsigned long long u64t;

__device__ __forceinline__ float sigf(float x) { return 1.0f / (1.0f + expf(-x)); }

#define DOT4(a, xv, wv)                                              \
  a = fmaf((xv).x, (wv).x, a); a = fmaf((xv).y, (wv).y, a);          \
  a = fmaf((xv).z, (wv).z, a); a = fmaf((xv).w, (wv).w, a);

// Agent-scope (sc1) 16B load: bypasses stale per-XCD L2 (fallback tier only).
__device__ __forceinline__ float4 ld_h4_sc1(const float4* p) {
  const u64t* q = (const u64t*)p;
  u64t a = __hip_atomic_load(q,     __ATOMIC_RELAXED, __HIP_MEMORY_SCOPE_AGENT);
  u64t b = __hip_atomic_load(q + 1, __ATOMIC_RELAXED, __HIP_MEMORY_SCOPE_AGENT);
  union { u64t u; float2 f; } ca, cb;
  ca.u = a; cb.u = b;
  return make_float4(ca.f.x, ca.f.y, cb.f.x, cb.f.y);
}

// Grid barrier without cache invalidation (h visibility via sc1 stores +
// fresh/deterministic ring buffers read with plain loads).
__device__ __forceinline__ void gridbar(unsigned* c) {
  __syncthreads();   // drains vmcnt: all sc1 h-stores have reached the LLC
  if (threadIdx.x == 0) {
    __hip_atomic_fetch_add(c, 1u, __ATOMIC_RELEASE, __HIP_MEMORY_SCOPE_AGENT);
    while (__hip_atomic_load(c, __ATOMIC_RELAXED, __HIP_MEMORY_SCOPE_AGENT) < gridDim.x) {
      __builtin_amdgcn_s_sleep(1);
    }
  }
  __syncthreads();
}

// Transpose X[b][t][0:512] -> XT4[t][kq][b].
__global__ __launch_bounds__(256) void xt_kernel(
    const float* __restrict__ X, float4* __restrict__ XT4)
{
  int idx = blockIdx.x * 256 + threadIdx.x;     // over 100*128*128
  int b  = idx & 127;
  int kq = (idx >> 7) & 127;
  int t  = idx >> 14;
  XT4[idx] = *(const float4*)(X + ((size_t)b * T_ + t) * IN_ + kq * 4);
}

// 6 broadcast ds_reads + 12 DOT4 pairs for one k-quad
#define GEMM_Q(q, x0, x1, ANA0, ANA1, ANB0, ANB1)                                  \
  {                                                                                \
    float4 wrA = wlds[wbRA + (q)], wzA = wlds[wbZA + (q)], wnA = wlds[wbNA + (q)]; \
    float4 wrB = wlds[wbRB + (q)], wzB = wlds[wbZB + (q)], wnB = wlds[wbNB + (q)]; \
    DOT4(arA0, x0, wrA); DOT4(arA1, x1, wrA);                                      \
    DOT4(azA0, x0, wzA); DOT4(azA1, x1, wzA);                                      \
    DOT4(ANA0, x0, wnA); DOT4(ANA1, x1, wnA);                                      \
    DOT4(arB0, x0, wrB); DOT4(arB1, x1, wrB);                                      \
    DOT4(azB0, x0, wzB); DOT4(azB1, x1, wzB);                                      \
    DOT4(ANB0, x0, wnB); DOT4(ANB1, x1, wnB);                                      \
  }

// Persistent main GRU: 256 blocks x 1024 threads (16 waves, 4/SIMD), 1 block/CU.
// Weights live in LDS (loaded once, read via wave-uniform broadcast ds_read_b128;
// each weight quad read by exactly ONE wave per step -> no scalar-cache refills).
// Wave = (j-pair jlg) x (K/8 slice ks), covering all 128 batches (x0/x1).
// RING=true: per-step h buffers, plain L2-cached h loads; else sc1 ping-pong.
template<bool RING>
__global__ __launch_bounds__(1024, 4) void gru_persist3(
    const float* __restrict__ X, const float4* __restrict__ XT4, int use_xt,
    const float* __restrict__ wih, const float* __restrict__ whh,
    const float* __restrict__ bih, const float* __restrict__ bhh,
    float* __restrict__ ring,                     // [R][H/4][128] float4
    unsigned* __restrict__ barr)
{
  extern __shared__ float4 wlds[];                // [4608] weights | [8*4*128] reduce
  float4* const red4 = wlds + WQ_;                // 64 KB

  const int tid  = threadIdx.x;
  const int lane = tid & 63;
  const int w    = __builtin_amdgcn_readfirstlane(tid >> 6);   // 0..15
  const int jlg  = w & 1;                         // j-pair group
  const int ks   = w >> 1;                        // K slice 0..7
  const int j0   = blockIdx.x << 2;

  // ---- one-time: weights -> LDS  (4 j-rows x 3 gates x 384 quads, x|h merged)
  for (int idx = tid; idx < WQ_; idx += 1024) {
    int jj  = idx / 1152;
    int rem = idx - jj * 1152;
    int g   = rem / 384;
    int q   = rem - g * 384;
    float4 v;
    if (q < 128) v = *(const float4*)(wih + (size_t)(g * H_ + j0 + jj) * IN_ + q * 4);
    else         v = *(const float4*)(whh + (size_t)(g * H_ + j0 + jj) * H_ + (q - 128) * 4);
    wlds[(jj * 3 + g) * 384 + q] = v;
  }

  // wave-uniform LDS bases (float4 index)
  const int jjA  = jlg * 2, jjB = jjA + 1;
  const int wbRA = (jjA * 3 + 0) * 384, wbZA = (jjA * 3 + 1) * 384, wbNA = (jjA * 3 + 2) * 384;
  const int wbRB = (jjB * 3 + 0) * 384, wbZB = (jjB * 3 + 1) * 384, wbNB = (jjB * 3 + 2) * 384;
  const int qs = ks * 48, qe = qs + 48;
  const int qx_end   = (qe < 128) ? qe : 128;     // end of X sub-range
  const int qh_start = (qs > 128) ? qs : 128;     // start of H sub-range

  // epilogue mapping + biases (threads 0..511: jl 0..3 x b 0..127)
  const int ejl = tid >> 7;
  const int eb  = tid & 127;
  float bir = 0.f, biz = 0.f, bin = 0.f, bhr = 0.f, bhz = 0.f, bhn = 0.f;
  if (tid < 512) {
    const int j = j0 + ejl;
    bir = bih[j]; biz = bih[H_ + j]; bin = bih[2 * H_ + j];
    bhr = bhh[j]; bhz = bhh[H_ + j]; bhn = bhh[2 * H_ + j];
  }

  __syncthreads();

  for (int t = 0; t < T_; ++t) {
    const float4* __restrict__ hp4 =
        (const float4*)ring + (size_t)(RING ? t : (t & 1)) * 32768;
    float* __restrict__ hnf =
        ring + (size_t)(RING ? (t + 1) : ((t + 1) & 1)) * 131072;

    float arA0=0.f, arA1=0.f, azA0=0.f, azA1=0.f, anxA0=0.f, anxA1=0.f, anhA0=0.f, anhA1=0.f;
    float arB0=0.f, arB1=0.f, azB0=0.f, azB1=0.f, anxB0=0.f, anxB1=0.f, anhB0=0.f, anhB1=0.f;

    // ---- X sub-range
    if (use_xt) {
      const float4* __restrict__ xt = XT4 + (size_t)t * 16384 + lane;
      #pragma unroll 4
      for (int q = qs; q < qx_end; ++q) {
        float4 x0 = xt[q * 128];
        float4 x1 = xt[q * 128 + 64];
        GEMM_Q(q, x0, x1, anxA0, anxA1, anxB0, anxB1);
      }
    } else {
      const float* xr0 = X + ((size_t)lane * T_ + t) * IN_;
      const float* xr1 = X + ((size_t)(lane + 64) * T_ + t) * IN_;
      #pragma unroll 4
      for (int q = qs; q < qx_end; ++q) {
        float4 x0 = *(const float4*)(xr0 + q * 4);
        float4 x1 = *(const float4*)(xr1 + q * 4);
        GEMM_Q(q, x0, x1, anxA0, anxA1, anxB0, anxB1);
      }
    }

    // ---- H sub-range
    {
      const float4* __restrict__ hb = hp4 + lane;
      #pragma unroll 4
      for (int q = qh_start; q < qe; ++q) {
        float4 x0, x1;
        if (RING) { x0 = hb[(q - 128) * 128]; x1 = hb[(q - 128) * 128 + 64]; }
        else      { x0 = ld_h4_sc1(hb + (q - 128) * 128);
                    x1 = ld_h4_sc1(hb + (q - 128) * 128 + 64); }
        GEMM_Q(q, x0, x1, anhA0, anhA1, anhB0, anhB1);
      }
    }

    // ---- 8-way cross-wave K reduction via LDS (64 KB region)
    red4[((ks * 4 + jjA) << 7) + lane]      = make_float4(arA0, azA0, anxA0, anhA0);
    red4[((ks * 4 + jjA) << 7) + lane + 64] = make_float4(arA1, azA1, anxA1, anhA1);
    red4[((ks * 4 + jjB) << 7) + lane]      = make_float4(arB0, azB0, anxB0, anhB0);
    red4[((ks * 4 + jjB) << 7) + lane + 64] = make_float4(arB1, azB1, anxB1, anhB1);
    __syncthreads();

    if (tid < 512) {
      float sr = 0.f, sz = 0.f, sx = 0.f, sh = 0.f;
      #pragma unroll
      for (int k2 = 0; k2 < 8; ++k2) {
        float4 v = red4[((k2 * 4 + ejl) << 7) + eb];
        sr += v.x; sz += v.y; sx += v.z; sh += v.w;
      }
      float r = sigf(sr + bir + bhr);
      float z = sigf(sz + biz + bhz);
      float n = tanhf(sx + bin + r * (sh + bhn));
      const int hidx = ((blockIdx.x * 128 + eb) << 2) + ejl;
      float hpv;
      if (RING) hpv = ((const float*)hp4)[hidx];
      else      hpv = __hip_atomic_load(&((const float*)hp4)[hidx],
                                        __ATOMIC_RELAXED, __HIP_MEMORY_SCOPE_AGENT);
      float hv = (1.f - z) * n + z * hpv;
      __hip_atomic_store(&hnf[hidx], hv, __ATOMIC_RELAXED, __HIP_MEMORY_SCOPE_AGENT);
    }

    gridbar(barr + t);   // trailing syncthreads protects red4 reuse next step
  }
}

// Final h4T -> hfin[b][k]
__global__ __launch_bounds__(256) void hfin_kernel(
    const float* __restrict__ h4, float* __restrict__ out)
{
  int idx = blockIdx.x * 256 + threadIdx.x;   // over 128*1024
  int b = idx >> 10, k = idx & 1023;
  out[idx] = h4[(((k >> 2) * 128 + b) << 2) + (k & 3)];
}

// Gating GRUs: one wave per batch, gate-per-lane, all state in regs.
__global__ __launch_bounds__(64, 1) void gating_kernel(
    const float* __restrict__ X,
    const float* __restrict__ gwih0, const float* __restrict__ gwhh0,
    const float* __restrict__ gbih0, const float* __restrict__ gbhh0,
    const float* __restrict__ gwih1, const float* __restrict__ gwhh1,
    const float* __restrict__ gbih1, const float* __restrict__ gbhh1,
    float* __restrict__ omega)
{
  const int b = blockIdx.x;
  const int g = threadIdx.x;
  const int u = g & 7;
  float wi0[GIN_] = {}, wh0[GH_] = {}, wi1[GH_] = {}, wh1[GH_] = {};
  float bi0 = 0.f, bh0 = 0.f, bi1 = 0.f, bh1 = 0.f;
  if (g < 3 * GH_) {
    #pragma unroll
    for (int i = 0; i < GIN_; ++i) wi0[i] = gwih0[g * GIN_ + i];
    #pragma unroll
    for (int k = 0; k < GH_; ++k) { wh0[k] = gwhh0[g * GH_ + k]; wi1[k] = gwih1[g * GH_ + k]; wh1[k] = gwhh1[g * GH_ + k]; }
    bi0 = gbih0[g]; bh0 = gbhh0[g]; bi1 = gbih1[g]; bh1 = gbhh1[g];
  }
  float h0[GH_] = {}, h1[GH_] = {};
  for (int t = 0; t < T_; ++t) {
    float xt[GIN_];
    #pragma unroll
    for (int i = 0; i < GIN_; ++i) xt[i] = X[((size_t)b * T_ + t) * IN_ + (IN_ - GIN_) + i];
    float px = bi0, ph = bh0;
    #pragma unroll
    for (int i = 0; i < GIN_; ++i) px = fmaf(xt[i], wi0[i], px);
    #pragma unroll
    for (int k = 0; k < GH_; ++k) ph = fmaf(h0[k], wh0[k], ph);
    float s = px + ph;
    float s_r = __shfl(s, u);
    float s_z = __shfl(s, 8 + u);
    float nval = tanhf(px + sigf(s_r) * ph);
    float zval = sigf(s_z);
    float hnew = (1.f - zval) * nval + zval * h0[u];
    #pragma unroll
    for (int k = 0; k < GH_; ++k) h0[k] = __shfl(hnew, 16 + k);
    float px1 = bi1, ph1 = bh1;
    #pragma unroll
    for (int k = 0; k < GH_; ++k) px1 = fmaf(h0[k], wi1[k], px1);
    #pragma unroll
    for (int k = 0; k < GH_; ++k) ph1 = fmaf(h1[k], wh1[k], ph1);
    float s1 = px1 + ph1;
    float s1r = __shfl(s1, u);
    float s1z = __shfl(s1, 8 + u);
    float n1 = tanhf(px1 + sigf(s1r) * ph1);
    float z1 = sigf(s1z);
    float h1new = (1.f - z1) * n1 + z1 * h1[u];
    #pragma unroll
    for (int k = 0; k < GH_; ++k) h1[k] = __shfl(h1new, 16 + k);
  }
  if (g < GH_) {
    float m = h1[0];
    #pragma unroll
    for (int k = 1; k < GH_; ++k) m = fmaxf(m, h1[k]);
    float sum = 0.f;
    #pragma unroll
    for (int k = 0; k < GH_; ++k) sum += expf(h1[k] - m);
    omega[b * GH_ + g] = expf(h1[g] - m) / sum;
  }
}

// MoE layer: out[b,j] = act( sum_e omega[b,e] * (dot(in[b,:],w[e,:,j]) + bias[e,j]) )
__global__ __launch_bounds__(256, 2) void moe_kernel(
    const float* __restrict__ in, const float* __restrict__ w,
    const float* __restrict__ bias, const float* __restrict__ omega,
    float* __restrict__ out, int K, int act)
{
  __shared__ float4 lin4[64 * 32];
  __shared__ float  ldsw[E_ * 4 * 128];
  const int tid  = threadIdx.x;
  const int bh   = blockIdx.x & 1;
  const int jt   = blockIdx.x >> 1;
  const int wv   = tid >> 6;
  const int lane = tid & 63;
  const int j0   = jt * 4;
  const int j    = __builtin_amdgcn_readfirstlane(j0 + wv);
  const int b    = bh * 64 + lane;

  float acc[E_] = {0.f,0.f,0.f,0.f,0.f,0.f,0.f,0.f};
  const float4* row4 = &lin4[lane * 32];
  const int nch = K / 128;

  for (int c = 0; c < nch; ++c) {
    __syncthreads();
    const int k0 = c * 128;
    #pragma unroll
    for (int it = 0; it < 8; ++it) {
      int f = it * 256 + tid;
      int bb = f >> 5, q = f & 31;
      float4 v = *(const float4*)(in + (size_t)(bh * 64 + bb) * K + k0 + q * 4);
      lin4[bb * 32 + ((q & 24) | ((q ^ bb) & 7))] = v;
    }
    #pragma unroll
    for (int it = 0; it < 4; ++it) {
      int f = it * 256 + tid;
      int e = f >> 7, k = f & 127;
      float4 v = *(const float4*)(w + ((size_t)e * K + k0 + k) * HH_ + j0);
      ldsw[(e * 4 + 0) * 128 + k] = v.x;
      ldsw[(e * 4 + 1) * 128 + k] = v.y;
      ldsw[(e * 4 + 2) * 128 + k] = v.z;
      ldsw[(e * 4 + 3) * 128 + k] = v.w;
    }
    __syncthreads();
    #pragma unroll 2
    for (int q = 0; q < 32; ++q) {
      float4 xv = row4[(q & 24) | ((q ^ lane) & 7)];
      #pragma unroll
      for (int e = 0; e < E_; ++e) {
        const float4 wq = *(const float4*)&ldsw[(e * 4 + wv) * 128 + 4 * q];
        acc[e] = fmaf(xv.x, wq.x, acc[e]);
        acc[e] = fmaf(xv.y, wq.y, acc[e]);
        acc[e] = fmaf(xv.z, wq.z, acc[e]);
        acc[e] = fmaf(xv.w, wq.w, acc[e]);
      }
    }
  }

  float om[E_];
  #pragma unroll
  for (int e = 0; e < E_; ++e) om[e] = omega[b * E_ + e];
  float v = 0.f;
  #pragma unroll
  for (int e = 0; e < E_; ++e) v = fmaf(om[e], acc[e] + bias[e * HH_ + j], v);
  if (act == 0) v = (v > 0.f) ? v : expm1f(v);
  else          v = fminf(fmaxf(v, 0.f), 1.f);
  out[(size_t)b * HH_ + j] = v;
}

extern "C" void kernel_launch(void* const* d_in, const int* in_sizes, int n_in,
                              void* d_out, int out_size, void* d_ws, size_t ws_size,
                              hipStream_t stream) {
  (void)in_sizes; (void)n_in; (void)out_size;
  const float* X     = (const float*)d_in[0];
  const float* gwih0 = (const float*)d_in[1];
  const float* gwhh0 = (const float*)d_in[2];
  const float* gbih0 = (const float*)d_in[3];
  const float* gbhh0 = (const float*)d_in[4];
  const float* gwih1 = (const float*)d_in[5];
  const float* gwhh1 = (const float*)d_in[6];
  const float* gbih1 = (const float*)d_in[7];
  const float* gbhh1 = (const float*)d_in[8];
  const float* mwih  = (const float*)d_in[9];
  const float* mwhh  = (const float*)d_in[10];
  const float* mbih  = (const float*)d_in[11];
  const float* mbhh  = (const float*)d_in[12];
  const float* w1    = (const float*)d_in[13];
  const float* b1    = (const float*)d_in[14];
  const float* w2    = (const float*)d_in[15];
  const float* b2    = (const float*)d_in[16];
  const float* w3    = (const float*)d_in[17];
  const float* b3    = (const float*)d_in[18];

  const size_t HBUF = (size_t)B_ * H_;                  // 131072 floats
  const size_t XTF  = (size_t)T_ * IN_ * B_;            // 6.55M floats
  size_t ringA = 256 + (size_t)(T_ + 1) * HBUF + HBUF + 1024 + 2 * (size_t)B_ * HH_ + XTF;
  size_t ringB = 256 + 2 * HBUF + HBUF + 1024 + 2 * (size_t)B_ * HH_ + XTF;
  int tierA   = ws_size >= ringA * sizeof(float);
  int use_xt  = tierA || (ws_size >= ringB * sizeof(float));
  int R       = tierA ? (T_ + 1) : 2;

  float* ws = (float*)d_ws;
  unsigned* barr = (unsigned*)ws;
  float* ring = ws + 256;
  float* hfin = ring + (size_t)R * HBUF;
  float* om   = hfin + HBUF;
  float* a1   = om + 1024;
  float* a2   = a1 + (size_t)B_ * HH_;
  float* XT   = a2 + (size_t)B_ * HH_;

  // zero: barrier slots + ring[0] (initial hidden state)
  hipMemsetAsync(d_ws, 0, (256 + HBUF) * sizeof(float), stream);
  const unsigned ldsz = (WQ_ + 8 * 4 * 128) * 16;       // 139264 B
  hipFuncSetAttribute((const void*)gru_persist3<true>,
                      hipFuncAttributeMaxDynamicSharedMemorySize, ldsz);
  hipFuncSetAttribute((const void*)gru_persist3<false>,
                      hipFuncAttributeMaxDynamicSharedMemorySize, ldsz);

  gating_kernel<<<128, 64, 0, stream>>>(X, gwih0, gwhh0, gbih0, gbhh0,
                                        gwih1, gwhh1, gbih1, gbhh1, om);
  if (use_xt)
    xt_kernel<<<(T_ * 128 * 128) / 256, 256, 0, stream>>>(X, (float4*)XT);

  if (tierA)
    gru_persist3<true><<<256, 1024, ldsz, stream>>>(X, (const float4*)XT, use_xt,
        mwih, mwhh, mbih, mbhh, ring, barr);
  else
    gru_persist3<false><<<256, 1024, ldsz, stream>>>(X, (const float4*)XT, use_xt,
        mwih, mwhh, mbih, mbhh, ring, barr);

  const float* hlast = ring + (size_t)(tierA ? T_ : (T_ & 1)) * HBUF;
  hfin_kernel<<<512, 256, 0, stream>>>(hlast, hfin);
  moe_kernel<<<256, 256, 0, stream>>>(hfin, w1, b1, om, a1, H_, 0);
  moe_kernel<<<256, 256, 0, stream>>>(a1, w2, b2, om, a2, HH_, 0);
  moe_kernel<<<256, 256, 0, stream>>>(a2, w3, b3, om, (float*)d_out, HH_, 1);
}

// Round 8
// 3245.983 us; speedup vs baseline: 1.8635x; 1.0590x over previous
//
#include <hip/hip_runtime.h>
#include <cmath>

#define B_   128
#define T_   100
#define IN_  512
#define H_   1024
#define E_   8
#define HH_  512
#define GIN_ 5
#define GH_  8
#define WQL_ 2304          // LDS-resident weight float4s (2 j-rows x 3 g x 384 q)

typedef unsigned long long u64t;

__device__ __forceinline__ float sigf(float x) { return 1.0f / (1.0f + expf(-x)); }

#define DOT4(a, xv, wv)                                              \
  a = fmaf((xv).x, (wv).x, a); a = fmaf((xv).y, (wv).y, a);          \
  a = fmaf((xv).z, (wv).z, a); a = fmaf((xv).w, (wv).w, a);

// Agent-scope (sc1) 16B load: bypasses stale per-XCD L2 (fallback tier only).
__device__ __forceinline__ float4 ld_h4_sc1(const float4* p) {
  const u64t* q = (const u64t*)p;
  u64t a = __hip_atomic_load(q,     __ATOMIC_RELAXED, __HIP_MEMORY_SCOPE_AGENT);
  u64t b = __hip_atomic_load(q + 1, __ATOMIC_RELAXED, __HIP_MEMORY_SCOPE_AGENT);
  union { u64t u; float2 f; } ca, cb;
  ca.u = a; cb.u = b;
  return make_float4(ca.f.x, ca.f.y, cb.f.x, cb.f.y);
}

// Grid barrier without cache invalidation (h visibility via sc1 stores +
// fresh/deterministic ring buffers read with plain loads).
__device__ __forceinline__ void gridbar(unsigned* c) {
  __syncthreads();   // drains vmcnt: all sc1 h-stores have reached the LLC
  if (threadIdx.x == 0) {
    __hip_atomic_fetch_add(c, 1u, __ATOMIC_RELEASE, __HIP_MEMORY_SCOPE_AGENT);
    while (__hip_atomic_load(c, __ATOMIC_RELAXED, __HIP_MEMORY_SCOPE_AGENT) < gridDim.x) {
      __builtin_amdgcn_s_sleep(1);
    }
  }
  __syncthreads();
}

// Transpose X[b][t][0:512] -> XT4[t][kq][b].
__global__ __launch_bounds__(256) void xt_kernel(
    const float* __restrict__ X, float4* __restrict__ XT4)
{
  int idx = blockIdx.x * 256 + threadIdx.x;     // over 100*128*128
  int b  = idx & 127;
  int kq = (idx >> 7) & 127;
  int t  = idx >> 14;
  XT4[idx] = *(const float4*)(X + ((size_t)b * T_ + t) * IN_ + kq * 4);
}

// A-row (even j) weights from LDS broadcast; B-row (odd j) via scalar s_load.
#define GEMM_QX(q, x0, x1)                                                         \
  {                                                                                \
    float4 wrA = wlds[wbRA + (q)], wzA = wlds[wbZA + (q)], wnA = wlds[wbNA + (q)]; \
    float4 wrB = xB_r[(q)], wzB = xB_z[(q)], wnB = xB_n[(q)];                      \
    DOT4(arA0, x0, wrA); DOT4(arA1, x1, wrA);                                      \
    DOT4(azA0, x0, wzA); DOT4(azA1, x1, wzA);                                      \
    DOT4(anxA0, x0, wnA); DOT4(anxA1, x1, wnA);                                    \
    DOT4(arB0, x0, wrB); DOT4(arB1, x1, wrB);                                      \
    DOT4(azB0, x0, wzB); DOT4(azB1, x1, wzB);                                      \
    DOT4(anxB0, x0, wnB); DOT4(anxB1, x1, wnB);                                    \
  }

#define GEMM_QH(q, x0, x1)                                                         \
  {                                                                                \
    float4 wrA = wlds[wbRA + (q)], wzA = wlds[wbZA + (q)], wnA = wlds[wbNA + (q)]; \
    float4 wrB = hB_r[(q) - 128], wzB = hB_z[(q) - 128], wnB = hB_n[(q) - 128];    \
    DOT4(arA0, x0, wrA); DOT4(arA1, x1, wrA);                                      \
    DOT4(azA0, x0, wzA); DOT4(azA1, x1, wzA);                                      \
    DOT4(anhA0, x0, wnA); DOT4(anhA1, x1, wnA);                                    \
    DOT4(arB0, x0, wrB); DOT4(arB1, x1, wrB);                                      \
    DOT4(azB0, x0, wzB); DOT4(azB1, x1, wzB);                                      \
    DOT4(anhB0, x0, wnB); DOT4(anhB1, x1, wnB);                                    \
  }

// Persistent main GRU: 256 blocks x 1024 threads (16 waves, 4/SIMD), 1 block/CU.
// Wave = (j-pair jlg) x (K/8 slice ks); weight delivery split across two pipes:
//   even j-row of the pair  -> LDS broadcast ds_read_b128 (27.6K cy/step)
//   odd  j-row of the pair  -> wave-uniform s_load from L2-hot rows (~20K cy)
// Each weight quad is still touched by exactly ONE wave per step.
// RING=true: per-step h buffers, plain L2-cached h loads; else sc1 ping-pong.
template<bool RING>
__global__ __launch_bounds__(1024, 4) void gru_persist4(
    const float* __restrict__ X, const float4* __restrict__ XT4, int use_xt,
    const float* __restrict__ wih, const float* __restrict__ whh,
    const float* __restrict__ bih, const float* __restrict__ bhh,
    float* __restrict__ ring,                     // [R][H/4][128] float4
    unsigned* __restrict__ barr)
{
  extern __shared__ float4 wlds[];                // [2304] weights | [8*4*128] reduce
  float4* const red4 = wlds + WQL_;               // 64 KB

  const int tid  = threadIdx.x;
  const int lane = tid & 63;
  const int w    = __builtin_amdgcn_readfirstlane(tid >> 6);   // 0..15
  const int jlg  = w & 1;                         // j-pair group
  const int ks   = w >> 1;                        // K slice 0..7
  const int j0   = blockIdx.x << 2;

  // ---- one-time: EVEN j-rows (j0+0, j0+2) x 3 gates -> LDS (x|h merged, 384 q)
  for (int idx = tid; idx < WQL_; idx += 1024) {
    int jj2 = idx / 1152;                         // 0,1 -> j-row j0 + 2*jj2
    int rem = idx - jj2 * 1152;
    int g   = rem / 384;
    int q   = rem - g * 384;
    float4 v;
    if (q < 128) v = *(const float4*)(wih + (size_t)(g * H_ + j0 + 2 * jj2) * IN_ + q * 4);
    else         v = *(const float4*)(whh + (size_t)(g * H_ + j0 + 2 * jj2) * H_ + (q - 128) * 4);
    wlds[(jj2 * 3 + g) * 384 + q] = v;
  }

  // wave-uniform LDS bases for the even row of this wave's pair
  const int wbRA = (jlg * 3 + 0) * 384, wbZA = (jlg * 3 + 1) * 384, wbNA = (jlg * 3 + 2) * 384;
  // wave-uniform global row pointers for the odd row (scalar path)
  const int jB = j0 + 2 * jlg + 1;
  const float4* const xB_r = (const float4*)(wih + (size_t)(0 * H_ + jB) * IN_);
  const float4* const xB_z = (const float4*)(wih + (size_t)(1 * H_ + jB) * IN_);
  const float4* const xB_n = (const float4*)(wih + (size_t)(2 * H_ + jB) * IN_);
  const float4* const hB_r = (const float4*)(whh + (size_t)(0 * H_ + jB) * H_);
  const float4* const hB_z = (const float4*)(whh + (size_t)(1 * H_ + jB) * H_);
  const float4* const hB_n = (const float4*)(whh + (size_t)(2 * H_ + jB) * H_);

  const int qs = ks * 48, qe = qs + 48;
  const int qx_end   = (qe < 128) ? qe : 128;
  const int qh_start = (qs > 128) ? qs : 128;

  // epilogue mapping + biases (threads 0..511: jl 0..3 x b 0..127)
  const int ejl = tid >> 7;
  const int eb  = tid & 127;
  float bir = 0.f, biz = 0.f, bin = 0.f, bhr = 0.f, bhz = 0.f, bhn = 0.f;
  if (tid < 512) {
    const int j = j0 + ejl;
    bir = bih[j]; biz = bih[H_ + j]; bin = bih[2 * H_ + j];
    bhr = bhh[j]; bhz = bhh[H_ + j]; bhn = bhh[2 * H_ + j];
  }

  __syncthreads();

  for (int t = 0; t < T_; ++t) {
    const float4* __restrict__ hp4 =
        (const float4*)ring + (size_t)(RING ? t : (t & 1)) * 32768;
    float* __restrict__ hnf =
        ring + (size_t)(RING ? (t + 1) : ((t + 1) & 1)) * 131072;

    float arA0=0.f, arA1=0.f, azA0=0.f, azA1=0.f, anxA0=0.f, anxA1=0.f, anhA0=0.f, anhA1=0.f;
    float arB0=0.f, arB1=0.f, azB0=0.f, azB1=0.f, anxB0=0.f, anxB1=0.f, anhB0=0.f, anhB1=0.f;

    // ---- X sub-range
    if (use_xt) {
      const float4* __restrict__ xt = XT4 + (size_t)t * 16384 + lane;
      #pragma unroll 4
      for (int q = qs; q < qx_end; ++q) {
        float4 x0 = xt[q * 128];
        float4 x1 = xt[q * 128 + 64];
        GEMM_QX(q, x0, x1);
      }
    } else {
      const float* xr0 = X + ((size_t)lane * T_ + t) * IN_;
      const float* xr1 = X + ((size_t)(lane + 64) * T_ + t) * IN_;
      #pragma unroll 4
      for (int q = qs; q < qx_end; ++q) {
        float4 x0 = *(const float4*)(xr0 + q * 4);
        float4 x1 = *(const float4*)(xr1 + q * 4);
        GEMM_QX(q, x0, x1);
      }
    }

    // ---- H sub-range
    {
      const float4* __restrict__ hb = hp4 + lane;
      #pragma unroll 4
      for (int q = qh_start; q < qe; ++q) {
        float4 x0, x1;
        if (RING) { x0 = hb[(q - 128) * 128]; x1 = hb[(q - 128) * 128 + 64]; }
        else      { x0 = ld_h4_sc1(hb + (q - 128) * 128);
                    x1 = ld_h4_sc1(hb + (q - 128) * 128 + 64); }
        GEMM_QH(q, x0, x1);
      }
    }

    // ---- 8-way cross-wave K reduction via LDS (64 KB region)
    {
      const int jjA = 2 * jlg, jjB_i = 2 * jlg + 1;
      red4[((ks * 4 + jjA) << 7) + lane]        = make_float4(arA0, azA0, anxA0, anhA0);
      red4[((ks * 4 + jjA) << 7) + lane + 64]   = make_float4(arA1, azA1, anxA1, anhA1);
      red4[((ks * 4 + jjB_i) << 7) + lane]      = make_float4(arB0, azB0, anxB0, anhB0);
      red4[((ks * 4 + jjB_i) << 7) + lane + 64] = make_float4(arB1, azB1, anxB1, anhB1);
    }
    __syncthreads();

    if (tid < 512) {
      float sr = 0.f, sz = 0.f, sx = 0.f, sh = 0.f;
      #pragma unroll
      for (int k2 = 0; k2 < 8; ++k2) {
        float4 v = red4[((k2 * 4 + ejl) << 7) + eb];
        sr += v.x; sz += v.y; sx += v.z; sh += v.w;
      }
      float r = sigf(sr + bir + bhr);
      float z = sigf(sz + biz + bhz);
      float n = tanhf(sx + bin + r * (sh + bhn));
      const int hidx = ((blockIdx.x * 128 + eb) << 2) + ejl;
      float hpv;
      if (RING) hpv = ((const float*)hp4)[hidx];
      else      hpv = __hip_atomic_load(&((const float*)hp4)[hidx],
                                        __ATOMIC_RELAXED, __HIP_MEMORY_SCOPE_AGENT);
      float hv = (1.f - z) * n + z * hpv;
      __hip_atomic_store(&hnf[hidx], hv, __ATOMIC_RELAXED, __HIP_MEMORY_SCOPE_AGENT);
    }

    gridbar(barr + t);   // trailing syncthreads protects red4 reuse next step
  }
}

// Final h4T -> hfin[b][k]
__global__ __launch_bounds__(256) void hfin_kernel(
    const float* __restrict__ h4, float* __restrict__ out)
{
  int idx = blockIdx.x * 256 + threadIdx.x;   // over 128*1024
  int b = idx >> 10, k = idx & 1023;
  out[idx] = h4[(((k >> 2) * 128 + b) << 2) + (k & 3)];
}

// Gating GRUs: one wave per batch, gate-per-lane, all state in regs.
__global__ __launch_bounds__(64, 1) void gating_kernel(
    const float* __restrict__ X,
    const float* __restrict__ gwih0, const float* __restrict__ gwhh0,
    const float* __restrict__ gbih0, const float* __restrict__ gbhh0,
    const float* __restrict__ gwih1, const float* __restrict__ gwhh1,
    const float* __restrict__ gbih1, const float* __restrict__ gbhh1,
    float* __restrict__ omega)
{
  const int b = blockIdx.x;
  const int g = threadIdx.x;
  const int u = g & 7;
  float wi0[GIN_] = {}, wh0[GH_] = {}, wi1[GH_] = {}, wh1[GH_] = {};
  float bi0 = 0.f, bh0 = 0.f, bi1 = 0.f, bh1 = 0.f;
  if (g < 3 * GH_) {
    #pragma unroll
    for (int i = 0; i < GIN_; ++i) wi0[i] = gwih0[g * GIN_ + i];
    #pragma unroll
    for (int k = 0; k < GH_; ++k) { wh0[k] = gwhh0[g * GH_ + k]; wi1[k] = gwih1[g * GH_ + k]; wh1[k] = gwhh1[g * GH_ + k]; }
    bi0 = gbih0[g]; bh0 = gbhh0[g]; bi1 = gbih1[g]; bh1 = gbhh1[g];
  }
  float h0[GH_] = {}, h1[GH_] = {};
  for (int t = 0; t < T_; ++t) {
    float xt[GIN_];
    #pragma unroll
    for (int i = 0; i < GIN_; ++i) xt[i] = X[((size_t)b * T_ + t) * IN_ + (IN_ - GIN_) + i];
    float px = bi0, ph = bh0;
    #pragma unroll
    for (int i = 0; i < GIN_; ++i) px = fmaf(xt[i], wi0[i], px);
    #pragma unroll
    for (int k = 0; k < GH_; ++k) ph = fmaf(h0[k], wh0[k], ph);
    float s = px + ph;
    float s_r = __shfl(s, u);
    float s_z = __shfl(s, 8 + u);
    float nval = tanhf(px + sigf(s_r) * ph);
    float zval = sigf(s_z);
    float hnew = (1.f - zval) * nval + zval * h0[u];
    #pragma unroll
    for (int k = 0; k < GH_; ++k) h0[k] = __shfl(hnew, 16 + k);
    float px1 = bi1, ph1 = bh1;
    #pragma unroll
    for (int k = 0; k < GH_; ++k) px1 = fmaf(h0[k], wi1[k], px1);
    #pragma unroll
    for (int k = 0; k < GH_; ++k) ph1 = fmaf(h1[k], wh1[k], ph1);
    float s1 = px1 + ph1;
    float s1r = __shfl(s1, u);
    float s1z = __shfl(s1, 8 + u);
    float n1 = tanhf(px1 + sigf(s1r) * ph1);
    float z1 = sigf(s1z);
    float h1new = (1.f - z1) * n1 + z1 * h1[u];
    #pragma unroll
    for (int k = 0; k < GH_; ++k) h1[k] = __shfl(h1new, 16 + k);
  }
  if (g < GH_) {
    float m = h1[0];
    #pragma unroll
    for (int k = 1; k < GH_; ++k) m = fmaxf(m, h1[k]);
    float sum = 0.f;
    #pragma unroll
    for (int k = 0; k < GH_; ++k) sum += expf(h1[k] - m);
    omega[b * GH_ + g] = expf(h1[g] - m) / sum;
  }
}

// MoE layer: out[b,j] = act( sum_e omega[b,e] * (dot(in[b,:],w[e,:,j]) + bias[e,j]) )
__global__ __launch_bounds__(256, 2) void moe_kernel(
    const float* __restrict__ in, const float* __restrict__ w,
    const float* __restrict__ bias, const float* __restrict__ omega,
    float* __restrict__ out, int K, int act)
{
  __shared__ float4 lin4[64 * 32];
  __shared__ float  ldsw[E_ * 4 * 128];
  const int tid  = threadIdx.x;
  const int bh   = blockIdx.x & 1;
  const int jt   = blockIdx.x >> 1;
  const int wv   = tid >> 6;
  const int lane = tid & 63;
  const int j0   = jt * 4;
  const int j    = __builtin_amdgcn_readfirstlane(j0 + wv);
  const int b    = bh * 64 + lane;

  float acc[E_] = {0.f,0.f,0.f,0.f,0.f,0.f,0.f,0.f};
  const float4* row4 = &lin4[lane * 32];
  const int nch = K / 128;

  for (int c = 0; c < nch; ++c) {
    __syncthreads();
    const int k0 = c * 128;
    #pragma unroll
    for (int it = 0; it < 8; ++it) {
      int f = it * 256 + tid;
      int bb = f >> 5, q = f & 31;
      float4 v = *(const float4*)(in + (size_t)(bh * 64 + bb) * K + k0 + q * 4);
      lin4[bb * 32 + ((q & 24) | ((q ^ bb) & 7))] = v;
    }
    #pragma unroll
    for (int it = 0; it < 4; ++it) {
      int f = it * 256 + tid;
      int e = f >> 7, k = f & 127;
      float4 v = *(const float4*)(w + ((size_t)e * K + k0 + k) * HH_ + j0);
      ldsw[(e * 4 + 0) * 128 + k] = v.x;
      ldsw[(e * 4 + 1) * 128 + k] = v.y;
      ldsw[(e * 4 + 2) * 128 + k] = v.z;
      ldsw[(e * 4 + 3) * 128 + k] = v.w;
    }
    __syncthreads();
    #pragma unroll 2
    for (int q = 0; q < 32; ++q) {
      float4 xv = row4[(q & 24) | ((q ^ lane) & 7)];
      #pragma unroll
      for (int e = 0; e < E_; ++e) {
        const float4 wq = *(const float4*)&ldsw[(e * 4 + wv) * 128 + 4 * q];
        acc[e] = fmaf(xv.x, wq.x, acc[e]);
        acc[e] = fmaf(xv.y, wq.y, acc[e]);
        acc[e] = fmaf(xv.z, wq.z, acc[e]);
        acc[e] = fmaf(xv.w, wq.w, acc[e]);
      }
    }
  }

  float om[E_];
  #pragma unroll
  for (int e = 0; e < E_; ++e) om[e] = omega[b * E_ + e];
  float v = 0.f;
  #pragma unroll
  for (int e = 0; e < E_; ++e) v = fmaf(om[e], acc[e] + bias[e * HH_ + j], v);
  if (act == 0) v = (v > 0.f) ? v : expm1f(v);
  else          v = fminf(fmaxf(v, 0.f), 1.f);
  out[(size_t)b * HH_ + j] = v;
}

extern "C" void kernel_launch(void* const* d_in, const int* in_sizes, int n_in,
                              void* d_out, int out_size, void* d_ws, size_t ws_size,
                              hipStream_t stream) {
  (void)in_sizes; (void)n_in; (void)out_size;
  const float* X     = (const float*)d_in[0];
  const float* gwih0 = (const float*)d_in[1];
  const float* gwhh0 = (const float*)d_in[2];
  const float* gbih0 = (const float*)d_in[3];
  const float* gbhh0 = (const float*)d_in[4];
  const float* gwih1 = (const float*)d_in[5];
  const float* gwhh1 = (const float*)d_in[6];
  const float* gbih1 = (const float*)d_in[7];
  const float* gbhh1 = (const float*)d_in[8];
  const float* mwih  = (const float*)d_in[9];
  const float* mwhh  = (const float*)d_in[10];
  const float* mbih  = (const float*)d_in[11];
  const float* mbhh  = (const float*)d_in[12];
  const float* w1    = (const float*)d_in[13];
  const float* b1    = (const float*)d_in[14];
  const float* w2    = (const float*)d_in[15];
  const float* b2    = (const float*)d_in[16];
  const float* w3    = (const float*)d_in[17];
  const float* b3    = (const float*)d_in[18];

  const size_t HBUF = (size_t)B_ * H_;                  // 131072 floats
  const size_t XTF  = (size_t)T_ * IN_ * B_;            // 6.55M floats
  size_t ringA = 256 + (size_t)(T_ + 1) * HBUF + HBUF + 1024 + 2 * (size_t)B_ * HH_ + XTF;
  size_t ringB = 256 + 2 * HBUF + HBUF + 1024 + 2 * (size_t)B_ * HH_ + XTF;
  int tierA   = ws_size >= ringA * sizeof(float);
  int use_xt  = tierA || (ws_size >= ringB * sizeof(float));
  int R       = tierA ? (T_ + 1) : 2;

  float* ws = (float*)d_ws;
  unsigned* barr = (unsigned*)ws;
  float* ring = ws + 256;
  float* hfin = ring + (size_t)R * HBUF;
  float* om   = hfin + HBUF;
  float* a1   = om + 1024;
  float* a2   = a1 + (size_t)B_ * HH_;
  float* XT   = a2 + (size_t)B_ * HH_;

  // zero: barrier slots + ring[0] (initial hidden state)
  hipMemsetAsync(d_ws, 0, (256 + HBUF) * sizeof(float), stream);
  const unsigned ldsz = (WQL_ + 8 * 4 * 128) * 16;      // 102400 B
  hipFuncSetAttribute((const void*)gru_persist4<true>,
                      hipFuncAttributeMaxDynamicSharedMemorySize, ldsz);
  hipFuncSetAttribute((const void*)gru_persist4<false>,
                      hipFuncAttributeMaxDynamicSharedMemorySize, ldsz);

  gating_kernel<<<128, 64, 0, stream>>>(X, gwih0, gwhh0, gbih0, gbhh0,
                                        gwih1, gwhh1, gbih1, gbhh1, om);
  if (use_xt)
    xt_kernel<<<(T_ * 128 * 128) / 256, 256, 0, stream>>>(X, (float4*)XT);

  if (tierA)
    gru_persist4<true><<<256, 1024, ldsz, stream>>>(X, (const float4*)XT, use_xt,
        mwih, mwhh, mbih, mbhh, ring, barr);
  else
    gru_persist4<false><<<256, 1024, ldsz, stream>>>(X, (const float4*)XT, use_xt,
        mwih, mwhh, mbih, mbhh, ring, barr);

  const float* hlast = ring + (size_t)(tierA ? T_ : (T_ & 1)) * HBUF;
  hfin_kernel<<<512, 256, 0, stream>>>(hlast, hfin);
  moe_kernel<<<256, 256, 0, stream>>>(hfin, w1, b1, om, a1, H_, 0);
  moe_kernel<<<256, 256, 0, stream>>>(a1, w2, b2, om, a2, HH_, 0);
  moe_kernel<<<256, 256, 0, stream>>>(a2, w3, b3, om, (float*)d_out, HH_, 1);
}